// Round 7
// baseline (640.646 us; speedup 1.0000x reference)
//
#include <hip/hip_runtime.h>

#define TT 65
#define DD 32
#define HH 128
#define NSTEP 64

typedef __attribute__((ext_vector_type(8))) short bf16x8;
typedef __attribute__((ext_vector_type(4))) float f32x4;
typedef __attribute__((ext_vector_type(4))) unsigned int u32x4;

__device__ constexpr float ATc[6][5] = {
    {0.f, 0.f, 0.f, 0.f, 0.f},
    {0.2f, 0.f, 0.f, 0.f, 0.f},
    {3.f/40.f, 9.f/40.f, 0.f, 0.f, 0.f},
    {44.f/45.f, -56.f/15.f, 32.f/9.f, 0.f, 0.f},
    {19372.f/6561.f, -25360.f/2187.f, 64448.f/6561.f, -212.f/729.f, 0.f},
    {9017.f/3168.f, -355.f/33.f, 46732.f/5247.f, 49.f/176.f, -5103.f/18656.f}
};
__device__ constexpr float BTc[6] = {35.f/384.f, 0.f, 500.f/1113.f, 125.f/192.f,
                                     -2187.f/6784.f, 11.f/84.f};

struct Frag3 { bf16x8 h, m, l; };

__device__ __forceinline__ float tanh_fast(float x) {
    float e = __expf(2.0f * x);
    return fmaf(-2.0f, __builtin_amdgcn_rcpf(e + 1.0f), 1.0f);
}

// 3-term bf16 truncation split: v = h + m + l + O(2^-24 |v|), exact residuals.
__device__ __forceinline__ Frag3 split8(const float* v) {
    unsigned int wh[4], wm[4], wl[4];
    #pragma unroll
    for (int p = 0; p < 4; ++p) {
        float a = v[2*p], b = v[2*p+1];
        unsigned int ua = __float_as_uint(a), ub = __float_as_uint(b);
        unsigned int uam = ua & 0xFFFF0000u, ubm = ub & 0xFFFF0000u;
        wh[p] = ubm | (ua >> 16);
        float ra = a - __uint_as_float(uam);
        float rb = b - __uint_as_float(ubm);
        unsigned int ura = __float_as_uint(ra), urb = __float_as_uint(rb);
        unsigned int uram = ura & 0xFFFF0000u, urbm = urb & 0xFFFF0000u;
        wm[p] = urbm | (ura >> 16);
        float sa = ra - __uint_as_float(uram);
        float sb = rb - __uint_as_float(urbm);
        wl[p] = (__float_as_uint(sb) & 0xFFFF0000u) | (__float_as_uint(sa) >> 16);
    }
    Frag3 f;
    u32x4 H = {wh[0], wh[1], wh[2], wh[3]};
    u32x4 M = {wm[0], wm[1], wm[2], wm[3]};
    u32x4 L = {wl[0], wl[1], wl[2], wl[3]};
    f.h = __builtin_bit_cast(bf16x8, H);
    f.m = __builtin_bit_cast(bf16x8, M);
    f.l = __builtin_bit_cast(bf16x8, L);
    return f;
}

// Split 2 scalars into 3 packed bf16-pair words (lo half = a, hi half = b).
__device__ __forceinline__ void split2pack(float a, float b,
                                           unsigned int& ph, unsigned int& pm,
                                           unsigned int& pl) {
    unsigned int ua = __float_as_uint(a), ub = __float_as_uint(b);
    unsigned int ham = ua & 0xFFFF0000u, hbm = ub & 0xFFFF0000u;
    ph = (ua >> 16) | hbm;
    float ra = a - __uint_as_float(ham);
    float rb = b - __uint_as_float(hbm);
    unsigned int ura = __float_as_uint(ra), urb = __float_as_uint(rb);
    unsigned int ram = ura & 0xFFFF0000u, rbm = urb & 0xFFFF0000u;
    pm = (ura >> 16) | rbm;
    float sa = ra - __uint_as_float(ram);
    float sb = rb - __uint_as_float(rbm);
    pl = (__float_as_uint(sa) >> 16) | (__float_as_uint(sb) & 0xFFFF0000u);
}

// 6-product split accumulate, 2 independent chains of 3 (shorter dep chain).
__device__ __forceinline__ f32x4 mac3b(const Frag3& A, const Frag3& B, f32x4 cinit) {
    f32x4 a0 = cinit;
    f32x4 a1 = {0.f, 0.f, 0.f, 0.f};
    a0 = __builtin_amdgcn_mfma_f32_16x16x32_bf16(A.h, B.h, a0, 0, 0, 0);
    a1 = __builtin_amdgcn_mfma_f32_16x16x32_bf16(A.h, B.m, a1, 0, 0, 0);
    a0 = __builtin_amdgcn_mfma_f32_16x16x32_bf16(A.m, B.h, a0, 0, 0, 0);
    a1 = __builtin_amdgcn_mfma_f32_16x16x32_bf16(A.m, B.m, a1, 0, 0, 0);
    a0 = __builtin_amdgcn_mfma_f32_16x16x32_bf16(A.l, B.h, a0, 0, 0, 0);
    a1 = __builtin_amdgcn_mfma_f32_16x16x32_bf16(A.h, B.l, a1, 0, 0, 0);
    #pragma unroll
    for (int i = 0; i < 4; ++i) a0[i] += a1[i];
    return a0;
}

// Block = 4 waves, 32 rows = TWO independent 16-row groups per wave (ILP-2,
// shared weight registers). Per stage: compute(X)+compute(Y) -> barrier ->
// reduce/publish(X)+reduce/publish(Y) -> barrier. One barrier per group-stage
// (half of R6) and every chain has a sibling to interleave with.
// Grid = 256 blocks = 1 block/CU.
__global__ __launch_bounds__(256, 1)
void NeuralODE_dopri5_r7(const float* __restrict__ x, const float* __restrict__ t,
                         const float* __restrict__ W1, const float* __restrict__ b1,
                         const float* __restrict__ W2, const float* __restrict__ b2,
                         float* __restrict__ out)
{
    __shared__ unsigned int ytp[2][3][16][16];       // [group][plane][row][16 u32]
    __shared__ __align__(16) float zb[2][4][512];    // [group][wave][row*32+c]
    __shared__ __align__(16) float pb[2][4][512];    // [group][wave][row*32+d]

    const int tid = threadIdx.x;
    const int w   = tid >> 6;
    const int l   = tid & 63;
    const int r   = l & 15;
    const int q   = l >> 4;
    const int g   = (r >> 1) & 3;                    // plane block swizzle
    const int swz = (r & 7) << 2;                    // f32-block swizzle (proven)
    const int d0  = 8 * w + 2 * q;                   // owned state pair

    // ---- static weight fragments (shared by both groups) ----
    Frag3 W1f[2], W2f[2];
    f32x4 b1f[2];
    {
        float v[8];
        #pragma unroll
        for (int i = 0; i < 2; ++i) {
            int m = 2 * w + i;
            *(f32x4*)&v[0] = *(const f32x4*)&W1[(16*m + r) * DD + 8*q];
            *(f32x4*)&v[4] = *(const f32x4*)&W1[(16*m + r) * DD + 8*q + 4];
            W1f[i] = split8(v);
            b1f[i] = *(const f32x4*)&b1[16*m + 4*q];
        }
        #pragma unroll
        for (int m2 = 0; m2 < 2; ++m2) {
            *(f32x4*)&v[0] = *(const f32x4*)&W2[(16*m2 + r) * HH + 32*w + 8*q];
            *(f32x4*)&v[4] = *(const f32x4*)&W2[(16*m2 + r) * HH + 32*w + 8*q + 4];
            W2f[m2] = split8(v);
        }
    }
    const float b2x = b2[d0], b2y = b2[d0 + 1];

    // ---- h via lane shuffle (t row 0 is uniform) ----
    const float h_all = t[l + 1] - t[l];

    // ---- per-group state ----
    float yx[2], yy[2], kxs[2][5], kys[2][5], bax[2], bay[2];
    #pragma unroll
    for (int gg = 0; gg < 2; ++gg) {
        const int row = blockIdx.x * 32 + gg * 16 + r;
        float2 y0 = *(const float2*)&x[(size_t)row * (TT*DD) + d0];
        yx[gg] = y0.x; yy[gg] = y0.y;
        unsigned int ph, pm, pl;
        split2pack(y0.x, y0.y, ph, pm, pl);
        ytp[gg][0][r][((w ^ g) << 2) + q] = ph;
        ytp[gg][1][r][((w ^ g) << 2) + q] = pm;
        ytp[gg][2][r][((w ^ g) << 2) + q] = pl;
        *(float2*)&out[(size_t)row * (TT*DD) + d0] = y0;
    }
    __syncthreads();

    #pragma unroll 1
    for (int step = 0; step < NSTEP; ++step) {
        const float h = __shfl(h_all, step);
        bax[0] = bax[1] = 0.f;
        bay[0] = bay[1] = 0.f;

        #pragma unroll
        for (int s = 0; s < 6; ++s) {
            // ---------- compute phase: both groups, interleaved chains ----------
            #pragma unroll
            for (int gg = 0; gg < 2; ++gg) {
                Frag3 B1;
                B1.h = __builtin_bit_cast(bf16x8, *(const u32x4*)&ytp[gg][0][r][(q ^ g) << 2]);
                B1.m = __builtin_bit_cast(bf16x8, *(const u32x4*)&ytp[gg][1][r][(q ^ g) << 2]);
                B1.l = __builtin_bit_cast(bf16x8, *(const u32x4*)&ytp[gg][2][r][(q ^ g) << 2]);

                f32x4 z0 = mac3b(W1f[0], B1, b1f[0]);
                f32x4 z1 = mac3b(W1f[1], B1, b1f[1]);
                #pragma unroll
                for (int e = 0; e < 4; ++e) { z0[e] = tanh_fast(z0[e]); z1[e] = tanh_fast(z1[e]); }

                *(f32x4*)&zb[gg][w][r * 32 + ((     4*q) ^ swz)] = z0;
                *(f32x4*)&zb[gg][w][r * 32 + ((16 + 4*q) ^ swz)] = z1;
                float vz[8];
                *(f32x4*)&vz[0] = *(const f32x4*)&zb[gg][w][r * 32 + ((8*q)     ^ swz)];
                *(f32x4*)&vz[4] = *(const f32x4*)&zb[gg][w][r * 32 + ((8*q + 4) ^ swz)];
                Frag3 B2 = split8(vz);

                const f32x4 zero = {0.f, 0.f, 0.f, 0.f};
                f32x4 p0 = mac3b(W2f[0], B2, zero);
                f32x4 p1 = mac3b(W2f[1], B2, zero);
                *(f32x4*)&pb[gg][w][r * 32 + ((     4*q) ^ swz)] = p0;
                *(f32x4*)&pb[gg][w][r * 32 + ((16 + 4*q) ^ swz)] = p1;
            }
            __syncthreads();

            // ---------- owner phase: reduce, Butcher update, publish planes ----------
            #pragma unroll
            for (int gg = 0; gg < 2; ++gg) {
                float kx = b2x, ky = b2y;
                #pragma unroll
                for (int v4 = 0; v4 < 4; ++v4) {
                    float2 pp = *(const float2*)&pb[gg][v4][r * 32 + (d0 ^ swz)];
                    kx += pp.x; ky += pp.y;
                }
                if (s < 5) { kxs[gg][s] = kx; kys[gg][s] = ky; }
                bax[gg] = fmaf(BTc[s], kx, bax[gg]);
                bay[gg] = fmaf(BTc[s], ky, bay[gg]);

                float ytx, yty;
                if (s < 5) {
                    float ax = ATc[s+1][s] * kx;
                    float ay = ATc[s+1][s] * ky;
                    #pragma unroll
                    for (int j = 0; j < 5; ++j)
                        if (j < s) { ax = fmaf(ATc[s+1][j], kxs[gg][j], ax);
                                     ay = fmaf(ATc[s+1][j], kys[gg][j], ay); }
                    ytx = fmaf(h, ax, yx[gg]);
                    yty = fmaf(h, ay, yy[gg]);
                } else {
                    yx[gg] = fmaf(h, bax[gg], yx[gg]);
                    yy[gg] = fmaf(h, bay[gg], yy[gg]);
                    ytx = yx[gg]; yty = yy[gg];
                    const int row = blockIdx.x * 32 + gg * 16 + r;
                    float2 yn = {yx[gg], yy[gg]};
                    *(float2*)&out[(size_t)row * (TT*DD) + (size_t)(step+1) * DD + d0] = yn;
                }
                unsigned int ph, pm, pl;
                split2pack(ytx, yty, ph, pm, pl);
                ytp[gg][0][r][((w ^ g) << 2) + q] = ph;
                ytp[gg][1][r][((w ^ g) << 2) + q] = pm;
                ytp[gg][2][r][((w ^ g) << 2) + q] = pl;
            }
            __syncthreads();
        }
    }
}

extern "C" void kernel_launch(void* const* d_in, const int* in_sizes, int n_in,
                              void* d_out, int out_size, void* d_ws, size_t ws_size,
                              hipStream_t stream) {
    (void)in_sizes; (void)n_in; (void)d_ws; (void)ws_size; (void)out_size;
    const float* x  = (const float*)d_in[0];
    const float* t  = (const float*)d_in[1];
    // d_in[2] = itv, d_in[3] = itv_mask : unused by the reference math
    const float* W1 = (const float*)d_in[4];
    const float* b1 = (const float*)d_in[5];
    const float* W2 = (const float*)d_in[6];
    const float* b2 = (const float*)d_in[7];
    float* out = (float*)d_out;

    dim3 grid(8192 / 32);   // 256 blocks x 4 waves, 2 row-groups per wave
    dim3 block(256);
    hipLaunchKernelGGL(NeuralODE_dopri5_r7, grid, block, 0, stream,
                       x, t, W1, b1, W2, b2, out);
}